// Round 5
// baseline (232.209 us; speedup 1.0000x reference)
//
#include <hip/hip_runtime.h>
#include <cstddef>

#define BATCH 8
#define NQ 16384
#define NK 16384
#define FEAT 128
#define MID 16
#define CTXD 128
#define OUTD 128
#define EPSV 1e-5f

// ws layout (float units)
#define OFF_LAM 0          // [8][16][128] = 16384
#define OFF_ST  16384      // [2][16] BN stats (+pad) = 64
#define OFF_SW  16448      // [8][16] sumw fallback = 128
#define OFF_U   16576      // [8][16][128] fallback = 16384 -> ends 32960
#define OFF_E   32960      // E^T bf16 [8][128][128] = 131072 shorts = 65536 float-slots -> ends 98496
#define OFF_S   98496      // sumw partials [8][16][128] = 16384 -> ends 114880
#define OFF_P   114880     // U partials [8][128][16][128] = 2097152
#define NEED_FLOATS (114880 + 2097152)

typedef __attribute__((ext_vector_type(8))) short bf16x8;
typedef __attribute__((ext_vector_type(4))) float f32x4;

__device__ __forceinline__ short f2bf(float x) {
    union { float f; unsigned u; } v; v.f = x;
    unsigned r = v.u + 0x7fffu + ((v.u >> 16) & 1u);   // RNE
    return (short)(r >> 16);
}
__device__ __forceinline__ bf16x8 pack8(float4 a, float4 b) {
    bf16x8 r;
    r[0] = f2bf(a.x); r[1] = f2bf(a.y); r[2] = f2bf(a.z); r[3] = f2bf(a.w);
    r[4] = f2bf(b.x); r[5] = f2bf(b.y); r[6] = f2bf(b.z); r[7] = f2bf(b.w);
    return r;
}

// ---------------------------------------------------------------------------
// Phase 1: block = 128 ctx rows (2 sub-slabs of 64).
//  - ctx slab -> LDS f32, XOR-swizzled 16B chunks (conflict-free b128 reads)
//  - key = ctx@Wk via MFMA 16x16x32 bf16 (Wk^T bf16 in LDS)
//  - w = exp(key) -> wL (tiny LDS), U += w^T@ctx in f32 VALU
//  - epilogue: per-block partials (or atomics fallback)
// ---------------------------------------------------------------------------
template <bool PARTIALS>
__global__ __launch_bounds__(256) void k_phase1(
    const float* __restrict__ ctx, const float* __restrict__ Wk,
    float* __restrict__ P, float* __restrict__ S,
    float* __restrict__ U, float* __restrict__ sumwG)
{
    __shared__ float cL[64 * 128];      // 32768 B, swizzled chunks
    __shared__ short wkT[16 * 136];     // 4352 B  (Wk^T bf16, row stride 136)
    __shared__ float wL[64 * 20];       // 5120 B
    __shared__ float swred[4][16];      // 256 B
    const int b = blockIdx.y, blk = blockIdx.x, t = threadIdx.x;
    const int lane = t & 63;
    const int wid  = __builtin_amdgcn_readfirstlane(t >> 6);
    const int rlo = lane & 15, h = lane >> 4;

    // stage Wk^T bf16 (coalesced read; e = k*16+m)
    #pragma unroll
    for (int i = 0; i < 8; ++i) {
        int e = t + 256 * i;
        wkT[(e & 15) * 136 + (e >> 4)] = f2bf(Wk[e]);
    }

    float a00=0.f,a01=0.f,a10=0.f,a11=0.f,a20=0.f,a21=0.f,a30=0.f,a31=0.f;
    float sw = 0.f;
    const size_t rowbase = (size_t)b * NK + (size_t)blk * 128;

    for (int s = 0; s < 2; ++s) {
        __syncthreads();   // cL/wL free; wkT visible (first iter)
        {
            const float4* g4 = (const float4*)(ctx + (rowbase + 64 * s) * CTXD);
            #pragma unroll
            for (int i = 0; i < 8; ++i) {
                int idx = t + 256 * i;
                int r = idx >> 5, c = idx & 31;
                ((float4*)cL)[r * 32 + (c ^ (r & 7))] = g4[idx];
            }
        }
        __syncthreads();

        // ---- key GEMM (MFMA): wave owns rows wid*16..+15 ----
        const int row = wid * 16 + rlo;
        f32x4 kacc = {0.f, 0.f, 0.f, 0.f};
        #pragma unroll
        for (int ks = 0; ks < 4; ++ks) {
            float4 A0 = ((const float4*)cL)[row * 32 + ((8*ks + 2*h)     ^ (row & 7))];
            float4 A1 = ((const float4*)cL)[row * 32 + ((8*ks + 2*h + 1) ^ (row & 7))];
            bf16x8 af = pack8(A0, A1);
            bf16x8 bq = *(const bf16x8*)(wkT + rlo * 136 + 32*ks + 8*h);
            kacc = __builtin_amdgcn_mfma_f32_16x16x32_bf16(af, bq, kacc, 0, 0, 0);
        }
        // lane holds key[tile row 4h+r][m=rlo]
        float w0 = __expf(kacc[0]);
        float w1 = __expf(kacc[1]);
        float w2 = __expf(kacc[2]);
        float w3 = __expf(kacc[3]);
        sw += w0 + w1 + w2 + w3;
        const int nb = wid * 16 + 4 * h;
        wL[(nb + 0) * 20 + rlo] = w0;
        wL[(nb + 1) * 20 + rlo] = w1;
        wL[(nb + 2) * 20 + rlo] = w2;
        wL[(nb + 3) * 20 + rlo] = w3;
        __syncthreads();

        // ---- U accumulate (f32): wave owns mids 4*wid..+3, lane owns d=2l,2l+1
        #pragma unroll 8
        for (int n = 0; n < 64; ++n) {
            float4 w4 = *(const float4*)(wL + n * 20 + 4 * wid);   // broadcast
            const float2 c2 = *(const float2*)((const char*)cL + n * 512
                               + ((((lane >> 1) ^ (n & 7))) << 4) + ((lane & 1) << 3));
            a00 += w4.x * c2.x; a01 += w4.x * c2.y;
            a10 += w4.y * c2.x; a11 += w4.y * c2.y;
            a20 += w4.z * c2.x; a21 += w4.z * c2.y;
            a30 += w4.w * c2.x; a31 += w4.w * c2.y;
        }
    }

    if (PARTIALS) {
        float2* p0 = (float2*)(P + (((size_t)b * 128 + blk) * 16 + 4 * wid) * 128 + 2 * lane);
        p0[0]   = make_float2(a00, a01);
        p0[64]  = make_float2(a10, a11);
        p0[128] = make_float2(a20, a21);
        p0[192] = make_float2(a30, a31);
    } else {
        float* u0 = U + ((size_t)b * 16 + 4 * wid) * 128 + 2 * lane;
        atomicAdd(u0 + 0,   a00); atomicAdd(u0 + 1,   a01);
        atomicAdd(u0 + 128, a10); atomicAdd(u0 + 129, a11);
        atomicAdd(u0 + 256, a20); atomicAdd(u0 + 257, a21);
        atomicAdd(u0 + 384, a30); atomicAdd(u0 + 385, a31);
    }
    // sumw: reduce lanes sharing m (=rlo) across h, then across waves
    sw += __shfl_xor(sw, 16);
    sw += __shfl_xor(sw, 32);
    if (lane < 16) swred[wid][lane] = sw;
    __syncthreads();
    if (t < 16) {
        float tot = swred[0][t] + swred[1][t] + swred[2][t] + swred[3][t];
        if (PARTIALS) S[((size_t)b * 16 + t) * 128 + blk] = tot;
        else          atomicAdd(&sumwG[b * 16 + t], tot);
    }
}

// ---------------------------------------------------------------------------
// Phase 2: reduce partials -> U row, lam = (U@Wv)/sumw, BN-stat atomics.
// ---------------------------------------------------------------------------
template <bool PARTIALS>
__global__ __launch_bounds__(256) void k_lam(
    const float* __restrict__ P, const float* __restrict__ S,
    const float* __restrict__ U, const float* __restrict__ sumwG,
    const float* __restrict__ Wv, float* __restrict__ lam, float* __restrict__ st)
{
    const int m = blockIdx.x, b = blockIdx.y, t = threadIdx.x;
    __shared__ float uL[128];
    __shared__ float red[256];
    __shared__ float swL;
    const int d = t & 127, h = t >> 7;

    float acc = 0.f;
    if (PARTIALS) {
        const float* p = P + ((size_t)b * 128 * 16 + m) * 128 + d;
        for (int blk = h; blk < 128; blk += 2) acc += p[(size_t)blk * 2048];
    } else {
        if (h == 0) acc = U[((size_t)b * 16 + m) * 128 + d];
    }
    red[t] = acc;

    if (t < 64) {
        float s;
        if (PARTIALS) {
            const float* sp = S + ((size_t)b * 16 + m) * 128;
            s = sp[t] + sp[t + 64];
            #pragma unroll
            for (int off = 32; off > 0; off >>= 1) s += __shfl_xor(s, off);
        } else {
            s = sumwG[b * 16 + m];
        }
        if (t == 0) swL = s;
    }
    __syncthreads();
    if (t < 128) uL[t] = red[t] + red[t + 128];
    __syncthreads();

    float dot = 0.f;
    const float* wv = Wv + h * 64 * OUTD + d;
    #pragma unroll 8
    for (int k = 0; k < 64; ++k) dot += uL[h * 64 + k] * wv[k * OUTD];
    red[t] = dot;
    __syncthreads();
    if (t < 128) {
        float l = (red[t] + red[t + 128]) / swL;
        lam[((size_t)b * 16 + m) * 128 + t] = l;
        float s1 = l, s2 = l * l;
        #pragma unroll
        for (int off = 32; off > 0; off >>= 1) {
            s1 += __shfl_xor(s1, off);
            s2 += __shfl_xor(s2, off);
        }
        if ((t & 63) == 0) {
            atomicAdd(&st[m], s1);
            atomicAdd(&st[16 + m], s2);
        }
    }
}

// ---------------------------------------------------------------------------
// Phase 2.5: E^T[b][d][k] = sum_m Wq[k][m]*bn[b][m][d], bf16. grid=(8), 256thr.
// ---------------------------------------------------------------------------
__global__ __launch_bounds__(256) void k_E(
    const float* __restrict__ lam, const float* __restrict__ st,
    const float* __restrict__ Wq, const float* __restrict__ gamma,
    const float* __restrict__ beta, short* __restrict__ Ebuf)
{
    const int b = blockIdx.x, t = threadIdx.x;
    __shared__ float bnL[16 * 128];
    __shared__ float wqL[128 * 20];
    #pragma unroll
    for (int i = 0; i < 8; ++i) {
        int e = t + 256 * i;                 // e = k*16+m
        wqL[(e >> 4) * 20 + (e & 15)] = Wq[e];
    }
    #pragma unroll
    for (int i = 0; i < 8; ++i) {
        int e = t + 256 * i;
        int m = e >> 7, d = e & 127;
        float mean = st[m] * (1.f / (BATCH * OUTD));
        float var  = st[16 + m] * (1.f / (BATCH * OUTD)) - mean * mean;
        bnL[m * 128 + d] = (lam[((size_t)b * 16 + m) * 128 + d] - mean)
                           * rsqrtf(var + EPSV) * gamma[m] + beta[m];
    }
    __syncthreads();
    const int k = t & 127, dh = t >> 7;
    float wq[16];
    #pragma unroll
    for (int j = 0; j < 4; ++j) {
        float4 v = ((const float4*)wqL)[k * 5 + j];
        wq[4*j] = v.x; wq[4*j+1] = v.y; wq[4*j+2] = v.z; wq[4*j+3] = v.w;
    }
    short* eb = Ebuf + (size_t)b * 16384;
    #pragma unroll 4
    for (int i = 0; i < 64; ++i) {
        int d = dh + 2 * i;                  // wave-uniform -> bnL broadcasts
        float s = 0.f;
        #pragma unroll
        for (int m = 0; m < 16; ++m) s += wq[m] * bnL[m * 128 + d];
        eb[d * 128 + k] = f2bf(s);
    }
}

// ---------------------------------------------------------------------------
// Phase 3: out = feat @ E  (bf16 MFMA, f32 accum). 64-row slabs, 4 waves.
// ---------------------------------------------------------------------------
__global__ __launch_bounds__(256) void k_out(
    const float* __restrict__ feat, const short* __restrict__ Ebuf,
    float* __restrict__ out)
{
    __shared__ short eL[128 * 128];      // 32 KiB, swizzled 16B chunks
    const int b = blockIdx.y, t = threadIdx.x;
    const int lane = t & 63;
    const int wid  = __builtin_amdgcn_readfirstlane(t >> 6);
    const int rlo = lane & 15, h = lane >> 4;
    const size_t r0 = (size_t)blockIdx.x * 64;

    {
        const float4* esrc = (const float4*)(Ebuf + (size_t)b * 16384);
        #pragma unroll
        for (int i = 0; i < 8; ++i) {
            int idx = t + 256 * i;           // 2048 chunks of 16B
            int r = idx >> 4, c = idx & 15;
            ((float4*)eL)[r * 16 + (c ^ (r & 15))] = esrc[idx];
        }
    }
    __syncthreads();

    const float* fbase = feat + ((size_t)b * NQ + r0 + wid * 16 + rlo) * FEAT + 8 * h;
    f32x4 acc[8];
    #pragma unroll
    for (int ct = 0; ct < 8; ++ct) acc[ct] = (f32x4){0.f, 0.f, 0.f, 0.f};

    #pragma unroll
    for (int ks = 0; ks < 4; ++ks) {
        float4 A0 = *(const float4*)(fbase + 32 * ks);
        float4 A1 = *(const float4*)(fbase + 32 * ks + 4);
        bf16x8 af = pack8(A0, A1);
        #pragma unroll
        for (int ct = 0; ct < 8; ++ct) {
            bf16x8 bq = *(const bf16x8*)(eL + ((ct * 16 + rlo) * 16 + ((4*ks + h) ^ rlo)) * 8);
            acc[ct] = __builtin_amdgcn_mfma_f32_16x16x32_bf16(af, bq, acc[ct], 0, 0, 0);
        }
    }
    float* obase = out + ((size_t)b * NQ + r0 + wid * 16 + 4 * h) * OUTD + rlo;
    #pragma unroll
    for (int ct = 0; ct < 8; ++ct) {
        #pragma unroll
        for (int r = 0; r < 4; ++r)
            obase[r * OUTD + ct * 16] = acc[ct][r];
    }
}

extern "C" void kernel_launch(void* const* d_in, const int* in_sizes, int n_in,
                              void* d_out, int out_size, void* d_ws, size_t ws_size,
                              hipStream_t stream)
{
    const float* feat  = (const float*)d_in[0];
    const float* ctx   = (const float*)d_in[1];
    const float* Wq    = (const float*)d_in[2];
    const float* Wk    = (const float*)d_in[3];
    const float* Wv    = (const float*)d_in[4];
    const float* gamma = (const float*)d_in[5];
    const float* beta  = (const float*)d_in[6];
    float* out = (float*)d_out;

    float* ws    = (float*)d_ws;
    float* lam   = ws + OFF_LAM;
    float* st    = ws + OFF_ST;
    float* sumwG = ws + OFF_SW;
    float* U     = ws + OFF_U;
    short* Ebuf  = (short*)(ws + OFF_E);
    float* S     = ws + OFF_S;
    float* P     = ws + OFF_P;

    const bool partials = ws_size >= (size_t)NEED_FLOATS * sizeof(float);

    if (partials) {
        hipMemsetAsync((char*)d_ws + OFF_ST * sizeof(float), 0, 64 * sizeof(float), stream);
        k_phase1<true><<<dim3(128, BATCH), 256, 0, stream>>>(ctx, Wk, P, S, U, sumwG);
        k_lam<true><<<dim3(MID, BATCH), 256, 0, stream>>>(P, S, U, sumwG, Wv, lam, st);
    } else {
        hipMemsetAsync((char*)d_ws + OFF_ST * sizeof(float), 0,
                       (OFF_U + 16384 - OFF_ST) * sizeof(float), stream);
        k_phase1<false><<<dim3(128, BATCH), 256, 0, stream>>>(ctx, Wk, P, S, U, sumwG);
        k_lam<false><<<dim3(MID, BATCH), 256, 0, stream>>>(P, S, U, sumwG, Wv, lam, st);
    }
    k_E<<<dim3(BATCH), 256, 0, stream>>>(lam, st, Wq, gamma, beta, Ebuf);
    k_out<<<dim3(NQ / 64, BATCH), 256, 0, stream>>>(feat, Ebuf, out);
}